// Round 2
// baseline (544.884 us; speedup 1.0000x reference)
//
#include <hip/hip_runtime.h>

// Sizes (fixed for this problem)
constexpr int B  = 2,  CIN = 2,  H = 64, W = 64, T = 350;
constexpr int C1 = 8;                       // conv1 out channels
constexpr int TO = 700, HO = 128, WO = 64;
constexpr int HW = H * W;                   // 4096

#define DEC 0.05000000074505806f            // (float)(1.0 - 0.95)

// ---------------------------------------------------------------------------
// Kernel 0: transpose x [B,2,H,W,T] -> xT [B,2,T,H,W] so conv reads coalesce.
// ---------------------------------------------------------------------------
__global__ void __launch_bounds__(256) transpose_kernel(
    const float* __restrict__ x, float* __restrict__ xT) {
  __shared__ float tile[64][65];
  int bid   = blockIdx.x;
  int tTile = bid % 6;            // 6 tiles of 64 cover T=350
  int slice = bid / 6;            // (b*2+ci)*64 + h
  int h  = slice % H;
  int bc = slice / H;             // b*2+ci
  int t0 = tTile * 64;
  int tx = threadIdx.x & 63;
  int tz = threadIdx.x >> 6;      // 0..3

  const float* src = x + ((long)bc * H + h) * (long)(W * T);
#pragma unroll
  for (int i = 0; i < 16; ++i) {
    int w = tz * 16 + i;
    int t = t0 + tx;
    tile[w][tx] = (t < T) ? src[(long)w * T + t] : 0.0f;
  }
  __syncthreads();
  float* dst = xT + ((long)bc * T) * HW + h * 64;
#pragma unroll
  for (int i = 0; i < 16; ++i) {
    int tl = tz * 16 + i;
    int t  = t0 + tl;
    if (t < T) dst[(long)t * HW + tx] = tile[tx][tl];
  }
}

// ---------------------------------------------------------------------------
// Kernel A: conv1(5x5 over T,H) + bias + relu + LIF1 + delta -> d8 int8
// d8 layout: [b][t][ci][hw]  (ci-major grouping within t for stage2 locality)
// block = 512 threads = (co 0..7) x (w 0..63), fixed (b,h,chunk).
// T chunked in 8 with 15-step warm-up (0.05^15 ~ 3e-20 -> bitwise converged).
// co forced wave-uniform via readfirstlane so weights s_load into SGPRs;
// row bases are block-uniform -> s-base + 32-bit v-offset addressing.
// ---------------------------------------------------------------------------
__global__ void __launch_bounds__(512, 4) convlif_kernel(
    const float* __restrict__ xT, const float* __restrict__ w1,
    const float* __restrict__ b1, signed char* __restrict__ d8) {
  int bid   = blockIdx.x;
  int chunk = bid & 7;
  int rest  = bid >> 3;
  int h = rest & 63;
  int b = rest >> 6;
  int w  = threadIdx.x & 63;
  int co = __builtin_amdgcn_readfirstlane(threadIdx.x >> 6);

  // Weights for this co (wave-uniform -> SGPRs); zero rows whose h+dh-2 is
  // out of range so clamped loads contribute nothing.
  float wt[2][5][5];
#pragma unroll
  for (int ci = 0; ci < 2; ++ci)
#pragma unroll
    for (int dt = 0; dt < 5; ++dt)
#pragma unroll
      for (int dh = 0; dh < 5; ++dh)
        wt[ci][dt][dh] = w1[((co * 2 + ci) * 5 + dt) * 5 + dh];
  float bias = b1[co];

  // Block-uniform row base pointers (no thread-varying component).
  const float* rowp[2][5];
#pragma unroll
  for (int ci = 0; ci < 2; ++ci)
#pragma unroll
    for (int dh = 0; dh < 5; ++dh) {
      int hh = h + dh - 2;
      bool hv = (hh >= 0) && (hh < H);
      int hc = hh < 0 ? 0 : (hh >= H - 1 ? H - 1 : hh);
      rowp[ci][dh] = xT + ((long)((b * 2 + ci) * T)) * HW + hc * 64;
      if (!hv) {
#pragma unroll
        for (int dt = 0; dt < 5; ++dt) wt[ci][dt][dh] = 0.0f;
      }
    }

  // chunk c: stored [45c, min(45c+45,350)); warm-up 15 steps before.
  int tstore = chunk * 45;
  int ts     = tstore ? tstore - 15 : 0;    // multiple of 5 (slot math)
  int te     = tstore + 45 < T ? tstore + 45 : T;

  // Sliding window win[ci][dh][slot], slot = tau % 5.
  float win[2][5][5];
#pragma unroll
  for (int ci = 0; ci < 2; ++ci)
#pragma unroll
    for (int dh = 0; dh < 5; ++dh) {
      const float* bp = rowp[ci][dh];
      win[ci][dh][3] = (ts >= 2) ? bp[(ts - 2) * HW + w] : 0.0f;
      win[ci][dh][4] = (ts >= 1) ? bp[(ts - 1) * HW + w] : 0.0f;
      win[ci][dh][0] = bp[(ts + 0) * HW + w];
      win[ci][dh][1] = bp[(ts + 1) * HW + w];
      win[ci][dh][2] = bp[(ts + 2) * HW + w];
    }

  signed char* dsto = d8 + ((long)(b * T) * C1 + co) * HW + h * 64 + w;

  float y = 0.0f, sprev = 0.0f;
  for (int tb = ts; tb < te; tb += 5) {
#pragma unroll
    for (int u = 0; u < 5; ++u) {
      int t = tb + u;
      float ac0 = 0.f, ac1 = 0.f, ac2 = 0.f, ac3 = 0.f;
#pragma unroll
      for (int ci = 0; ci < 2; ++ci)
#pragma unroll
        for (int dt = 0; dt < 5; ++dt) {
          const int slot = (u + dt + 3) % 5;
#pragma unroll
          for (int dh = 0; dh < 5; ++dh) {
            const int q = (ci * 25 + dt * 5 + dh) & 3;
            float p = win[ci][dh][slot] * wt[ci][dt][dh];
            if (q == 0) ac0 += p;
            else if (q == 1) ac1 += p;
            else if (q == 2) ac2 += p;
            else ac3 += p;
          }
        }
      float a = ((ac0 + ac1) + (ac2 + ac3)) + bias;
      a = fmaxf(a, 0.0f);
      y = fmaf(DEC, y, a);
      float s = (y >= 1.0f) ? 1.0f : 0.0f;
      if (t >= tstore) {
        float dlt = (t == 0) ? 0.0f : (s - sprev);
        dsto[(long)t * (C1 * HW)] = (signed char)dlt;
      }
      sprev = s;
      y = (s != 0.0f) ? 0.0f : y;
      // slide: load tau = t+3 into slot (u+3)%5
      int tau = t + 3;
      bool tv = tau < T;
      const int slot2 = (u + 3) % 5;
      int toff = tau * HW + w;
#pragma unroll
      for (int ci = 0; ci < 2; ++ci)
#pragma unroll
        for (int dh = 0; dh < 5; ++dh)
          win[ci][dh][slot2] = tv ? rowp[ci][dh][toff] : 0.0f;
    }
  }
}

// ---------------------------------------------------------------------------
// Kernel B: deconv(2x2,s2) + bias + relu + conv2(1x1) + LIF2 -> out
// out layout [B,2,H',W',T'], T' innermost; LDS-staged transposed flush.
// block = 64 threads (lane = w'), fixed (b,h',chunk of T'); 16 chunks.
// ---------------------------------------------------------------------------
__global__ void __launch_bounds__(64) stage2_kernel(
    const signed char* __restrict__ d8, const float* __restrict__ dw,
    const float* __restrict__ db, const float* __restrict__ cw,
    const float* __restrict__ cb, float* __restrict__ out) {
  __shared__ float SB[2][64][17];
  int bid   = blockIdx.x;
  int chunk = bid & 15;           // 16 chunks over T'=700
  int rest  = bid >> 4;
  int hp = rest & 127;            // h'
  int b  = rest >> 7;
  int wp = threadIdx.x;           // w'

  int h  = hp >> 1;
  int kh = 1 - (hp & 1);

  // deconv weights for this kh, both kt parities: dwk{kt}[c][ci]
  float dwk0[2][8], dwk1[2][8];
#pragma unroll
  for (int c = 0; c < 2; ++c)
#pragma unroll
    for (int ci = 0; ci < 8; ++ci) {
      dwk0[c][ci] = dw[((c * 8 + ci) * 2 + 0) * 2 + kh];
      dwk1[c][ci] = dw[((c * 8 + ci) * 2 + 1) * 2 + kh];
    }
  float db0 = db[0], db1 = db[1];
  float cw00 = cw[0], cw01 = cw[1], cw10 = cw[2], cw11 = cw[3];
  float cb0 = cb[0], cb1 = cb[1];

  int t0 = chunk * 44;
  int t1 = (t0 + 44 < TO) ? t0 + 44 : TO;   // last chunk: 40
  int tw = (t0 - 16 > 0) ? t0 - 16 : 0;     // 16-step LIF2 warm-up (even)

  const signed char* dbase = d8 + (long)b * T * C1 * HW + h * 64 + wp;
  float* outb = out + ((long)b * 2 * HO) * (long)(WO * TO);

  float y0 = 0.0f, y1 = 0.0f;
  float dv[8];
  for (int tp = tw; tp < t1; tp += 2) {
    int t = tp >> 1;
#pragma unroll
    for (int ci = 0; ci < 8; ++ci)
      dv[ci] = (float)dbase[((long)t * C1 + ci) * HW];

#pragma unroll
    for (int par = 0; par < 2; ++par) {     // par=0: tp (kt=1), par=1: tp+1 (kt=0)
      int tpp = tp + par;
      float v0 = db0, v1 = db1;
      if (par == 0) {
#pragma unroll
        for (int ci = 0; ci < 8; ++ci) {
          v0 = fmaf(dv[ci], dwk1[0][ci], v0);
          v1 = fmaf(dv[ci], dwk1[1][ci], v1);
        }
      } else {
#pragma unroll
        for (int ci = 0; ci < 8; ++ci) {
          v0 = fmaf(dv[ci], dwk0[0][ci], v0);
          v1 = fmaf(dv[ci], dwk0[1][ci], v1);
        }
      }
      v0 = fmaxf(v0, 0.0f);
      v1 = fmaxf(v1, 0.0f);
      float u0 = fmaf(cw00, v0, fmaf(cw01, v1, cb0));
      float u1 = fmaf(cw10, v0, fmaf(cw11, v1, cb1));
      y0 = fmaf(DEC, y0, u0);
      y1 = fmaf(DEC, y1, u1);
      float s0 = (y0 >= 1.0f) ? 1.0f : 0.0f;
      float s1 = (y1 >= 1.0f) ? 1.0f : 0.0f;
      y0 = (s0 != 0.0f) ? 0.0f : y0;
      y1 = (s1 != 0.0f) ? 0.0f : y1;

      if (tpp >= t0) {
        int k = (tpp - t0) & 15;
        SB[0][wp][k] = s0;
        SB[1][wp][k] = s1;
        if (par == 1 && (k == 15 || tpp == t1 - 1)) {
          __syncthreads();
          int Kc  = k + 1;                  // 16 or a multiple of 4
          int t0f = tpp - k;
#pragma unroll
          for (int o = 0; o < 2; ++o) {
            float* ob = outb + ((long)(o * HO + hp)) * (long)(WO * TO);
#pragma unroll
            for (int i = 0; i < 4; ++i) {
              int idx = (i << 6) + wp;
              int r   = idx >> 2;
              int c   = (idx & 3) << 2;
              if (c < Kc) {
                float4 vv;
                vv.x = SB[o][r][c + 0];
                vv.y = SB[o][r][c + 1];
                vv.z = SB[o][r][c + 2];
                vv.w = SB[o][r][c + 3];
                *reinterpret_cast<float4*>(ob + (long)r * TO + (t0f + c)) = vv;
              }
            }
          }
          __syncthreads();
        }
      }
    }
  }
}

// ---------------------------------------------------------------------------
extern "C" void kernel_launch(void* const* d_in, const int* in_sizes, int n_in,
                              void* d_out, int out_size, void* d_ws, size_t ws_size,
                              hipStream_t stream) {
  const float* x  = (const float*)d_in[0];
  const float* w1 = (const float*)d_in[1];
  const float* b1 = (const float*)d_in[2];
  const float* dw = (const float*)d_in[3];
  const float* db = (const float*)d_in[4];
  const float* cw = (const float*)d_in[5];
  const float* cb = (const float*)d_in[6];
  float* out = (float*)d_out;

  float* xT = (float*)d_ws;                                   // 22.94 MB
  signed char* d8 = (signed char*)d_ws + (size_t)B * CIN * T * HW * 4;  // +22.94 MB

  // 1) transpose x -> xT
  transpose_kernel<<<dim3(B * CIN * H * 6), dim3(256), 0, stream>>>(x, xT);
  // 2) conv1+relu+LIF1+delta -> d8 (8 T-chunks)
  convlif_kernel<<<dim3(B * H * 8), dim3(512), 0, stream>>>(xT, w1, b1, d8);
  // 3) deconv+relu+conv2+LIF2 -> out (16 T'-chunks)
  stage2_kernel<<<dim3(B * HO * 16), dim3(64), 0, stream>>>(d8, dw, db, cw, cb, out);
}

// Round 3
// 207.335 us; speedup vs baseline: 2.6280x; 2.6280x over previous
//
#include <hip/hip_runtime.h>

// Sizes (fixed for this problem)
constexpr int B  = 2,  CIN = 2,  H = 64, W = 64, T = 350;
constexpr int C1 = 8;                       // conv1 out channels
constexpr int TO = 700, HO = 128, WO = 64;
constexpr int HW = H * W;                   // 4096

#define DEC 0.05000000074505806f            // (float)(1.0 - 0.95)

// ---------------------------------------------------------------------------
// Kernel 0: transpose x [B,2,H,W,T] -> xT [B,2,T,H,W] so conv reads coalesce.
// ---------------------------------------------------------------------------
__global__ void __launch_bounds__(256) transpose_kernel(
    const float* __restrict__ x, float* __restrict__ xT) {
  __shared__ float tile[64][65];
  int bid   = blockIdx.x;
  int tTile = bid % 6;            // 6 tiles of 64 cover T=350
  int slice = bid / 6;            // (b*2+ci)*64 + h
  int h  = slice % H;
  int bc = slice / H;             // b*2+ci
  int t0 = tTile * 64;
  int tx = threadIdx.x & 63;
  int tz = threadIdx.x >> 6;      // 0..3

  const float* src = x + ((long)bc * H + h) * (long)(W * T);
#pragma unroll
  for (int i = 0; i < 16; ++i) {
    int w = tz * 16 + i;
    int t = t0 + tx;
    tile[w][tx] = (t < T) ? src[(long)w * T + t] : 0.0f;
  }
  __syncthreads();
  float* dst = xT + ((long)bc * T) * HW + h * 64;
#pragma unroll
  for (int i = 0; i < 16; ++i) {
    int tl = tz * 16 + i;
    int t  = t0 + tl;
    if (t < T) dst[(long)t * HW + tx] = tile[tx][tl];
  }
}

// ---------------------------------------------------------------------------
// Kernel A: conv1(5x5 over T,H) + bias + relu + LIF1 + delta -> d8 int8
// d8 layout: [b][t][ci][hw]  (t-major grouping for stage2 locality)
// block = 512 threads = (co 0..7) x (w 0..63), fixed (b,h,chunk).
// T chunked in 8 with 15-step warm-up (0.05^15 ~ 3e-20 -> bitwise converged).
// Body identical to the proven 88-VGPR round-1 version (no readfirstlane,
// no launch-bounds VGPR cap -> no scratch spill).
// ---------------------------------------------------------------------------
__global__ void __launch_bounds__(512, 2) convlif_kernel(
    const float* __restrict__ xT, const float* __restrict__ w1,
    const float* __restrict__ b1, signed char* __restrict__ d8) {
  int bid   = blockIdx.x;
  int chunk = bid & 7;
  int rest  = bid >> 3;
  int h = rest & 63;
  int b = rest >> 6;
  int w  = threadIdx.x & 63;
  int co = threadIdx.x >> 6;

  // Weights for this co; zero rows whose h+dh-2 is out of range so clamped
  // loads contribute nothing.
  float wt[2][5][5];
#pragma unroll
  for (int ci = 0; ci < 2; ++ci)
#pragma unroll
    for (int dt = 0; dt < 5; ++dt)
#pragma unroll
      for (int dh = 0; dh < 5; ++dh)
        wt[ci][dt][dh] = w1[((co * 2 + ci) * 5 + dt) * 5 + dh];
  float bias = b1[co];

  const float* base[2][5];
#pragma unroll
  for (int ci = 0; ci < 2; ++ci)
#pragma unroll
    for (int dh = 0; dh < 5; ++dh) {
      int hh = h + dh - 2;
      bool hv = (hh >= 0) && (hh < H);
      int hc = hh < 0 ? 0 : (hh >= H ? H - 1 : hh);
      base[ci][dh] = xT + ((long)((b * 2 + ci) * T)) * HW + hc * 64 + w;
      if (!hv) {
#pragma unroll
        for (int dt = 0; dt < 5; ++dt) wt[ci][dt][dh] = 0.0f;
      }
    }

  // chunk c: stored [45c, min(45c+45,350)); warm-up 15 steps before.
  int tstore = chunk * 45;
  int ts     = tstore ? tstore - 15 : 0;    // multiple of 5 (slot math)
  int te     = tstore + 45 < T ? tstore + 45 : T;

  // Sliding window win[ci][dh][slot], slot = tau % 5.
  float win[2][5][5];
#pragma unroll
  for (int ci = 0; ci < 2; ++ci)
#pragma unroll
    for (int dh = 0; dh < 5; ++dh) {
      const float* bp = base[ci][dh];
      win[ci][dh][3] = (ts >= 2) ? bp[(long)(ts - 2) * HW] : 0.0f;
      win[ci][dh][4] = (ts >= 1) ? bp[(long)(ts - 1) * HW] : 0.0f;
      win[ci][dh][0] = bp[(long)(ts + 0) * HW];
      win[ci][dh][1] = bp[(long)(ts + 1) * HW];
      win[ci][dh][2] = bp[(long)(ts + 2) * HW];
    }

  signed char* dsto = d8 + ((long)(b * T) * C1 + co) * HW + h * 64 + w;

  float y = 0.0f, sprev = 0.0f;
  for (int tb = ts; tb < te; tb += 5) {
#pragma unroll
    for (int u = 0; u < 5; ++u) {
      int t = tb + u;
      float ac0 = 0.f, ac1 = 0.f, ac2 = 0.f, ac3 = 0.f;
#pragma unroll
      for (int ci = 0; ci < 2; ++ci)
#pragma unroll
        for (int dt = 0; dt < 5; ++dt) {
          const int slot = (u + dt + 3) % 5;
#pragma unroll
          for (int dh = 0; dh < 5; ++dh) {
            const int q = (ci * 25 + dt * 5 + dh) & 3;
            float p = win[ci][dh][slot] * wt[ci][dt][dh];
            if (q == 0) ac0 += p;
            else if (q == 1) ac1 += p;
            else if (q == 2) ac2 += p;
            else ac3 += p;
          }
        }
      float a = ((ac0 + ac1) + (ac2 + ac3)) + bias;
      a = fmaxf(a, 0.0f);
      y = fmaf(DEC, y, a);
      float s = (y >= 1.0f) ? 1.0f : 0.0f;
      if (t >= tstore) {
        float dlt = (t == 0) ? 0.0f : (s - sprev);
        dsto[(long)t * (C1 * HW)] = (signed char)dlt;
      }
      sprev = s;
      y = (s != 0.0f) ? 0.0f : y;
      // slide: load tau = t+3 into slot (u+3)%5
      int tau = t + 3;
      bool tv = tau < T;
      const int slot2 = (u + 3) % 5;
#pragma unroll
      for (int ci = 0; ci < 2; ++ci)
#pragma unroll
        for (int dh = 0; dh < 5; ++dh)
          win[ci][dh][slot2] = tv ? base[ci][dh][(long)tau * HW] : 0.0f;
    }
  }
}

// ---------------------------------------------------------------------------
// Kernel B: deconv(2x2,s2) + bias + relu + conv2(1x1) + LIF2 -> out
// out layout [B,2,H',W',T'], T' innermost; LDS-staged transposed flush.
// block = 64 threads (lane = w'), fixed (b,h',chunk of T'); 16 chunks.
// ---------------------------------------------------------------------------
__global__ void __launch_bounds__(64) stage2_kernel(
    const signed char* __restrict__ d8, const float* __restrict__ dw,
    const float* __restrict__ db, const float* __restrict__ cw,
    const float* __restrict__ cb, float* __restrict__ out) {
  __shared__ float SB[2][64][17];
  int bid   = blockIdx.x;
  int chunk = bid & 15;           // 16 chunks over T'=700
  int rest  = bid >> 4;
  int hp = rest & 127;            // h'
  int b  = rest >> 7;
  int wp = threadIdx.x;           // w'

  int h  = hp >> 1;
  int kh = 1 - (hp & 1);

  // deconv weights for this kh, both kt parities: dwk{kt}[c][ci]
  float dwk0[2][8], dwk1[2][8];
#pragma unroll
  for (int c = 0; c < 2; ++c)
#pragma unroll
    for (int ci = 0; ci < 8; ++ci) {
      dwk0[c][ci] = dw[((c * 8 + ci) * 2 + 0) * 2 + kh];
      dwk1[c][ci] = dw[((c * 8 + ci) * 2 + 1) * 2 + kh];
    }
  float db0 = db[0], db1 = db[1];
  float cw00 = cw[0], cw01 = cw[1], cw10 = cw[2], cw11 = cw[3];
  float cb0 = cb[0], cb1 = cb[1];

  int t0 = chunk * 44;
  int t1 = (t0 + 44 < TO) ? t0 + 44 : TO;   // last chunk: 40
  int tw = (t0 - 16 > 0) ? t0 - 16 : 0;     // 16-step LIF2 warm-up (even)

  const signed char* dbase = d8 + (long)b * T * C1 * HW + h * 64 + wp;
  float* outb = out + ((long)b * 2 * HO) * (long)(WO * TO);

  float y0 = 0.0f, y1 = 0.0f;
  float dv[8];
  for (int tp = tw; tp < t1; tp += 2) {
    int t = tp >> 1;
#pragma unroll
    for (int ci = 0; ci < 8; ++ci)
      dv[ci] = (float)dbase[((long)t * C1 + ci) * HW];

#pragma unroll
    for (int par = 0; par < 2; ++par) {     // par=0: tp (kt=1), par=1: tp+1 (kt=0)
      int tpp = tp + par;
      float v0 = db0, v1 = db1;
      if (par == 0) {
#pragma unroll
        for (int ci = 0; ci < 8; ++ci) {
          v0 = fmaf(dv[ci], dwk1[0][ci], v0);
          v1 = fmaf(dv[ci], dwk1[1][ci], v1);
        }
      } else {
#pragma unroll
        for (int ci = 0; ci < 8; ++ci) {
          v0 = fmaf(dv[ci], dwk0[0][ci], v0);
          v1 = fmaf(dv[ci], dwk0[1][ci], v1);
        }
      }
      v0 = fmaxf(v0, 0.0f);
      v1 = fmaxf(v1, 0.0f);
      float u0 = fmaf(cw00, v0, fmaf(cw01, v1, cb0));
      float u1 = fmaf(cw10, v0, fmaf(cw11, v1, cb1));
      y0 = fmaf(DEC, y0, u0);
      y1 = fmaf(DEC, y1, u1);
      float s0 = (y0 >= 1.0f) ? 1.0f : 0.0f;
      float s1 = (y1 >= 1.0f) ? 1.0f : 0.0f;
      y0 = (s0 != 0.0f) ? 0.0f : y0;
      y1 = (s1 != 0.0f) ? 0.0f : y1;

      if (tpp >= t0) {
        int k = (tpp - t0) & 15;
        SB[0][wp][k] = s0;
        SB[1][wp][k] = s1;
        if (par == 1 && (k == 15 || tpp == t1 - 1)) {
          __syncthreads();
          int Kc  = k + 1;                  // 16 or a multiple of 4
          int t0f = tpp - k;
#pragma unroll
          for (int o = 0; o < 2; ++o) {
            float* ob = outb + ((long)(o * HO + hp)) * (long)(WO * TO);
#pragma unroll
            for (int i = 0; i < 4; ++i) {
              int idx = (i << 6) + wp;
              int r   = idx >> 2;
              int c   = (idx & 3) << 2;
              if (c < Kc) {
                float4 vv;
                vv.x = SB[o][r][c + 0];
                vv.y = SB[o][r][c + 1];
                vv.z = SB[o][r][c + 2];
                vv.w = SB[o][r][c + 3];
                *reinterpret_cast<float4*>(ob + (long)r * TO + (t0f + c)) = vv;
              }
            }
          }
          __syncthreads();
        }
      }
    }
  }
}

// ---------------------------------------------------------------------------
extern "C" void kernel_launch(void* const* d_in, const int* in_sizes, int n_in,
                              void* d_out, int out_size, void* d_ws, size_t ws_size,
                              hipStream_t stream) {
  const float* x  = (const float*)d_in[0];
  const float* w1 = (const float*)d_in[1];
  const float* b1 = (const float*)d_in[2];
  const float* dw = (const float*)d_in[3];
  const float* db = (const float*)d_in[4];
  const float* cw = (const float*)d_in[5];
  const float* cb = (const float*)d_in[6];
  float* out = (float*)d_out;

  float* xT = (float*)d_ws;                                   // 22.94 MB
  signed char* d8 = (signed char*)d_ws + (size_t)B * CIN * T * HW * 4;  // +22.94 MB

  // 1) transpose x -> xT
  transpose_kernel<<<dim3(B * CIN * H * 6), dim3(256), 0, stream>>>(x, xT);
  // 2) conv1+relu+LIF1+delta -> d8 (8 T-chunks)
  convlif_kernel<<<dim3(B * H * 8), dim3(512), 0, stream>>>(xT, w1, b1, d8);
  // 3) deconv+relu+conv2+LIF2 -> out (16 T'-chunks)
  stage2_kernel<<<dim3(B * HO * 16), dim3(64), 0, stream>>>(d8, dw, db, cw, cb, out);
}

// Round 4
// 122.465 us; speedup vs baseline: 4.4493x; 1.6930x over previous
//
#include <hip/hip_runtime.h>

// Sizes (fixed for this problem)
constexpr int B  = 2,  CIN = 2,  H = 64, W = 64, T = 350;
constexpr int C1 = 8;                       // conv1 out channels
constexpr int TO = 700, HO = 128, WO = 64;
constexpr int HW = H * W;                   // 4096

#define DEC 0.05000000074505806f            // (float)(1.0 - 0.95)

// ---------------------------------------------------------------------------
// Kernel 0: transpose x [B,2,H,W,T] -> xT [B,2,T,H,W] so conv reads coalesce.
// ---------------------------------------------------------------------------
__global__ void __launch_bounds__(256) transpose_kernel(
    const float* __restrict__ x, float* __restrict__ xT) {
  __shared__ float tile[64][65];
  int bid   = blockIdx.x;
  int tTile = bid % 6;            // 6 tiles of 64 cover T=350
  int slice = bid / 6;            // (b*2+ci)*64 + h
  int h  = slice % H;
  int bc = slice / H;             // b*2+ci
  int t0 = tTile * 64;
  int tx = threadIdx.x & 63;
  int tz = threadIdx.x >> 6;      // 0..3

  const float* src = x + ((long)bc * H + h) * (long)(W * T);
#pragma unroll
  for (int i = 0; i < 16; ++i) {
    int w = tz * 16 + i;
    int t = t0 + tx;
    tile[w][tx] = (t < T) ? src[(long)w * T + t] : 0.0f;
  }
  __syncthreads();
  float* dst = xT + ((long)bc * T) * HW + h * 64;
#pragma unroll
  for (int i = 0; i < 16; ++i) {
    int tl = tz * 16 + i;
    int t  = t0 + tl;
    if (t < T) dst[(long)t * HW + tx] = tile[tx][tl];
  }
}

// ---------------------------------------------------------------------------
// async global->LDS, 16 bytes per lane (wave-uniform LDS base + lane*16)
// ---------------------------------------------------------------------------
__device__ __forceinline__ void gload_lds16(const float* g, float* l) {
  __builtin_amdgcn_global_load_lds(
      (const __attribute__((address_space(1))) unsigned int*)g,
      (__attribute__((address_space(3))) unsigned int*)l, 16, 0, 0);
}

// ---------------------------------------------------------------------------
// Kernel A: conv1(5x5 over T,H) + bias + relu + LIF1 + delta -> d8 int8
// d8 layout: [b][t][ci][hw]. block = 512 = (co 0..7) x (w 0..63), grid (b,h,2).
// Double-buffered LDS pipeline: buffer k holds taus [ts+3+20k, ts+23+20k) as
// 200 rows (tau-major, (ci,dh)-minor) of 64 floats (+24 pad rows), staged by
// 7 global_load_lds(16B) per thread, synced by counted vmcnt(7) + s_barrier
// so next-buffer loads fly under 20 steps of compute. Inner-loop slide loads
// become ds_read_b32 with immediate offsets (2-way bank alias = free).
// ---------------------------------------------------------------------------
__global__ void __launch_bounds__(512) convlif_kernel(
    const float* __restrict__ xT, const float* __restrict__ w1,
    const float* __restrict__ b1, signed char* __restrict__ d8) {
  __shared__ float buf[2][224 * 64];        // 112 KiB
  const int tid = threadIdx.x;
  const int bid = blockIdx.x;
  const int chunk = bid & 1;
  const int rest  = bid >> 1;
  const int h = rest & 63;
  const int b = rest >> 6;
  const int w  = tid & 63;
  const int co = tid >> 6;                  // == wave id

  // Weights for this co; zero rows whose h+dh-2 is out of range.
  float wt[2][5][5];
#pragma unroll
  for (int ci = 0; ci < 2; ++ci)
#pragma unroll
    for (int dt = 0; dt < 5; ++dt)
#pragma unroll
      for (int dh = 0; dh < 5; ++dh)
        wt[ci][dt][dh] = w1[((co * 2 + ci) * 5 + dt) * 5 + dh];
  float bias = b1[co];

  // Clamped row bases for the one-time window init (global reads).
  const float* basep[2][5];
#pragma unroll
  for (int ci = 0; ci < 2; ++ci)
#pragma unroll
    for (int dh = 0; dh < 5; ++dh) {
      int hh = h + dh - 2;
      bool hv = (hh >= 0) && (hh < H);
      int hc = hh < 0 ? 0 : (hh > H - 1 ? H - 1 : hh);
      basep[ci][dh] = xT + ((long)((b * 2 + ci) * T)) * HW + hc * 64 + w;
      if (!hv) {
#pragma unroll
        for (int dt = 0; dt < 5; ++dt) wt[ci][dt][dh] = 0.0f;
      }
    }

  // Per-thread staging descriptors: 7 issues x 32 rows; row r -> (tau_loc,ci,dh).
  int tloc[7];
  int cpart[7];
#pragma unroll
  for (int i = 0; i < 7; ++i) {
    int r = (tid >> 4) + 32 * i;
    if (r > 199) r = 199;                   // pad rows duplicate row 199
    int tl  = r / 10;
    int rem = r - tl * 10;
    int ci  = rem / 5;
    int dh  = rem - ci * 5;
    int hh = h + dh - 2;
    int hc = hh < 0 ? 0 : (hh > H - 1 ? H - 1 : hh);
    tloc[i]  = tl;
    cpart[i] = ((b * 2 + ci) * T) * HW + hc * 64 + (tid & 15) * 4;
  }

  const int tstore = chunk ? 175 : 0;
  const int ts     = chunk ? 145 : 0;       // 30-step warm-up (bitwise converged)
  const int te     = chunk ? 350 : 175;
  const int nsup   = (te - ts + 19) / 20;   // 9 or 11 supersteps (20 steps each)

  // Prologue: stage buffer 0 (taus ts+3 .. ts+22).
  {
    int bs = ts + 3;
#pragma unroll
    for (int i = 0; i < 7; ++i) {
      int tau = bs + tloc[i];
      if (tau > T - 1) tau = T - 1;
      gload_lds16(xT + (long)cpart[i] + (long)tau * HW,
                  &buf[0][(i * 32 + co * 4) * 64]);
    }
  }

  // Init sliding window (taus ts-2..ts+2) from global; slot = tau % 5.
  float win[2][5][5];
#pragma unroll
  for (int ci = 0; ci < 2; ++ci)
#pragma unroll
    for (int dh = 0; dh < 5; ++dh) {
      const float* bp = basep[ci][dh];
      win[ci][dh][3] = (ts >= 2) ? bp[(long)(ts - 2) * HW] : 0.0f;
      win[ci][dh][4] = (ts >= 1) ? bp[(long)(ts - 1) * HW] : 0.0f;
      win[ci][dh][0] = bp[(long)(ts + 0) * HW];
      win[ci][dh][1] = bp[(long)(ts + 1) * HW];
      win[ci][dh][2] = bp[(long)(ts + 2) * HW];
    }

  asm volatile("s_waitcnt vmcnt(0)" ::: "memory");
  __builtin_amdgcn_s_barrier();
  asm volatile("" ::: "memory");

  signed char* dsto = d8 + ((long)(b * T) * C1 + co) * HW + h * 64 + w;

  float y = 0.0f, sprev = 0.0f;
  for (int k = 0; k < nsup; ++k) {
    asm volatile("" ::: "memory");
    __builtin_amdgcn_s_barrier();           // prior readers of buf[(k+1)&1] done
    asm volatile("" ::: "memory");
    if (k + 1 < nsup) {
      int bs = ts + 3 + 20 * (k + 1);
      float* nb = &buf[(k + 1) & 1][0];
#pragma unroll
      for (int i = 0; i < 7; ++i) {
        int tau = bs + tloc[i];
        if (tau > T - 1) tau = T - 1;
        gload_lds16(xT + (long)cpart[i] + (long)tau * HW,
                    nb + (i * 32 + co * 4) * 64);
      }
      // wait my buf[k&1] rows (7 newer ops = the loads just issued; older
      // stores drain too -- safe regardless of store count)
      asm volatile("s_waitcnt vmcnt(7)" ::: "memory");
    } else {
      asm volatile("s_waitcnt vmcnt(0)" ::: "memory");
    }
    __builtin_amdgcn_s_barrier();           // everyone's buf[k&1] rows arrived
    asm volatile("" ::: "memory");

    float* lb = &buf[k & 1][0];
    {
      // zero rows whose tau >= T (only last superstep of chunk 1)
      int bufstart = ts + 3 + 20 * k;
      int rz0 = (T - bufstart) * 10;
      if (rz0 < 200) {
        if (rz0 < 0) rz0 = 0;
        for (int r = rz0 + co; r < 200; r += 8) lb[r * 64 + w] = 0.0f;
        asm volatile("" ::: "memory");
        __builtin_amdgcn_s_barrier();
        asm volatile("" ::: "memory");
      }
    }

    const int t0s = ts + 20 * k;
    for (int jj = 0; jj < 4; ++jj) {
#pragma unroll
      for (int u = 0; u < 5; ++u) {
        const int j5 = jj * 5;
        int t = t0s + j5 + u;
        float ac0 = 0.f, ac1 = 0.f, ac2 = 0.f, ac3 = 0.f;
#pragma unroll
        for (int ci = 0; ci < 2; ++ci)
#pragma unroll
          for (int dt = 0; dt < 5; ++dt) {
            const int slot = (u + dt + 3) % 5;
#pragma unroll
            for (int dh = 0; dh < 5; ++dh) {
              const int q = (ci * 25 + dt * 5 + dh) & 3;
              float p = win[ci][dh][slot] * wt[ci][dt][dh];
              if (q == 0) ac0 += p;
              else if (q == 1) ac1 += p;
              else if (q == 2) ac2 += p;
              else ac3 += p;
            }
          }
        float a = ((ac0 + ac1) + (ac2 + ac3)) + bias;
        a = fmaxf(a, 0.0f);
        y = fmaf(DEC, y, a);
        float s = (y >= 1.0f) ? 1.0f : 0.0f;
        if (t >= tstore && t < te) {
          float dlt = (t == 0) ? 0.0f : (s - sprev);
          dsto[(long)t * (C1 * HW)] = (signed char)dlt;
        }
        sprev = s;
        y = (s != 0.0f) ? 0.0f : y;
        // slide: tau = t+3 lives at LDS row (j*10 + ci*5 + dh)
        const int slot2 = (u + 3) % 5;
#pragma unroll
        for (int ci = 0; ci < 2; ++ci)
#pragma unroll
          for (int dh = 0; dh < 5; ++dh)
            win[ci][dh][slot2] = lb[((j5 + u) * 10 + ci * 5 + dh) * 64 + w];
      }
    }
  }
}

// ---------------------------------------------------------------------------
// Kernel B: deconv(2x2,s2) + bias + relu + conv2(1x1) + LIF2 -> out
// out layout [B,2,H',W',T'], T' innermost; LDS-staged transposed flush.
// block = 64 threads (lane = w'), fixed (b,h',chunk of T'); 16 chunks.
// ---------------------------------------------------------------------------
__global__ void __launch_bounds__(64) stage2_kernel(
    const signed char* __restrict__ d8, const float* __restrict__ dw,
    const float* __restrict__ db, const float* __restrict__ cw,
    const float* __restrict__ cb, float* __restrict__ out) {
  __shared__ float SB[2][64][17];
  int bid   = blockIdx.x;
  int chunk = bid & 15;           // 16 chunks over T'=700
  int rest  = bid >> 4;
  int hp = rest & 127;            // h'
  int b  = rest >> 7;
  int wp = threadIdx.x;           // w'

  int h  = hp >> 1;
  int kh = 1 - (hp & 1);

  // deconv weights for this kh, both kt parities: dwk{kt}[c][ci]
  float dwk0[2][8], dwk1[2][8];
#pragma unroll
  for (int c = 0; c < 2; ++c)
#pragma unroll
    for (int ci = 0; ci < 8; ++ci) {
      dwk0[c][ci] = dw[((c * 8 + ci) * 2 + 0) * 2 + kh];
      dwk1[c][ci] = dw[((c * 8 + ci) * 2 + 1) * 2 + kh];
    }
  float db0 = db[0], db1 = db[1];
  float cw00 = cw[0], cw01 = cw[1], cw10 = cw[2], cw11 = cw[3];
  float cb0 = cb[0], cb1 = cb[1];

  int t0 = chunk * 44;
  int t1 = (t0 + 44 < TO) ? t0 + 44 : TO;   // last chunk: 40
  int tw = (t0 - 16 > 0) ? t0 - 16 : 0;     // 16-step LIF2 warm-up (even)

  const signed char* dbase = d8 + (long)b * T * C1 * HW + h * 64 + wp;
  float* outb = out + ((long)b * 2 * HO) * (long)(WO * TO);

  float y0 = 0.0f, y1 = 0.0f;
  float dv[8];
  for (int tp = tw; tp < t1; tp += 2) {
    int t = tp >> 1;
#pragma unroll
    for (int ci = 0; ci < 8; ++ci)
      dv[ci] = (float)dbase[((long)t * C1 + ci) * HW];

#pragma unroll
    for (int par = 0; par < 2; ++par) {     // par=0: tp (kt=1), par=1: tp+1 (kt=0)
      int tpp = tp + par;
      float v0 = db0, v1 = db1;
      if (par == 0) {
#pragma unroll
        for (int ci = 0; ci < 8; ++ci) {
          v0 = fmaf(dv[ci], dwk1[0][ci], v0);
          v1 = fmaf(dv[ci], dwk1[1][ci], v1);
        }
      } else {
#pragma unroll
        for (int ci = 0; ci < 8; ++ci) {
          v0 = fmaf(dv[ci], dwk0[0][ci], v0);
          v1 = fmaf(dv[ci], dwk0[1][ci], v1);
        }
      }
      v0 = fmaxf(v0, 0.0f);
      v1 = fmaxf(v1, 0.0f);
      float u0 = fmaf(cw00, v0, fmaf(cw01, v1, cb0));
      float u1 = fmaf(cw10, v0, fmaf(cw11, v1, cb1));
      y0 = fmaf(DEC, y0, u0);
      y1 = fmaf(DEC, y1, u1);
      float s0 = (y0 >= 1.0f) ? 1.0f : 0.0f;
      float s1 = (y1 >= 1.0f) ? 1.0f : 0.0f;
      y0 = (s0 != 0.0f) ? 0.0f : y0;
      y1 = (s1 != 0.0f) ? 0.0f : y1;

      if (tpp >= t0) {
        int k = (tpp - t0) & 15;
        SB[0][wp][k] = s0;
        SB[1][wp][k] = s1;
        if (par == 1 && (k == 15 || tpp == t1 - 1)) {
          __syncthreads();
          int Kc  = k + 1;                  // 16 or a multiple of 4
          int t0f = tpp - k;
#pragma unroll
          for (int o = 0; o < 2; ++o) {
            float* ob = outb + ((long)(o * HO + hp)) * (long)(WO * TO);
#pragma unroll
            for (int i = 0; i < 4; ++i) {
              int idx = (i << 6) + wp;
              int r   = idx >> 2;
              int c   = (idx & 3) << 2;
              if (c < Kc) {
                float4 vv;
                vv.x = SB[o][r][c + 0];
                vv.y = SB[o][r][c + 1];
                vv.z = SB[o][r][c + 2];
                vv.w = SB[o][r][c + 3];
                *reinterpret_cast<float4*>(ob + (long)r * TO + (t0f + c)) = vv;
              }
            }
          }
          __syncthreads();
        }
      }
    }
  }
}

// ---------------------------------------------------------------------------
extern "C" void kernel_launch(void* const* d_in, const int* in_sizes, int n_in,
                              void* d_out, int out_size, void* d_ws, size_t ws_size,
                              hipStream_t stream) {
  const float* x  = (const float*)d_in[0];
  const float* w1 = (const float*)d_in[1];
  const float* b1 = (const float*)d_in[2];
  const float* dw = (const float*)d_in[3];
  const float* db = (const float*)d_in[4];
  const float* cw = (const float*)d_in[5];
  const float* cb = (const float*)d_in[6];
  float* out = (float*)d_out;

  float* xT = (float*)d_ws;                                   // 22.94 MB
  signed char* d8 = (signed char*)d_ws + (size_t)B * CIN * T * HW * 4;  // +22.94 MB

  // 1) transpose x -> xT
  transpose_kernel<<<dim3(B * CIN * H * 6), dim3(256), 0, stream>>>(x, xT);
  // 2) conv1+relu+LIF1+delta -> d8 (2 T-chunks, LDS-pipelined)
  convlif_kernel<<<dim3(B * H * 2), dim3(512), 0, stream>>>(xT, w1, b1, d8);
  // 3) deconv+relu+conv2+LIF2 -> out (16 T'-chunks)
  stage2_kernel<<<dim3(B * HO * 16), dim3(64), 0, stream>>>(d8, dw, db, cw, cb, out);
}

// Round 5
// 121.630 us; speedup vs baseline: 4.4799x; 1.0069x over previous
//
#include <hip/hip_runtime.h>

// Sizes (fixed for this problem)
constexpr int B  = 2,  CIN = 2,  H = 64, W = 64, T = 350;
constexpr int C1 = 8;                       // conv1 out channels
constexpr int TO = 700, HO = 128, WO = 64;
constexpr int HW = H * W;                   // 4096

#define DEC 0.05000000074505806f            // (float)(1.0 - 0.95)

// ---------------------------------------------------------------------------
// Kernel 0: transpose x [B,2,H,W,T] -> xT [B,2,T,H,W] so conv reads coalesce.
// ---------------------------------------------------------------------------
__global__ void __launch_bounds__(256) transpose_kernel(
    const float* __restrict__ x, float* __restrict__ xT) {
  __shared__ float tile[64][65];
  int bid   = blockIdx.x;
  int tTile = bid % 6;            // 6 tiles of 64 cover T=350
  int slice = bid / 6;            // (b*2+ci)*64 + h
  int h  = slice % H;
  int bc = slice / H;             // b*2+ci
  int t0 = tTile * 64;
  int tx = threadIdx.x & 63;
  int tz = threadIdx.x >> 6;      // 0..3

  const float* src = x + ((long)bc * H + h) * (long)(W * T);
#pragma unroll
  for (int i = 0; i < 16; ++i) {
    int w = tz * 16 + i;
    int t = t0 + tx;
    tile[w][tx] = (t < T) ? src[(long)w * T + t] : 0.0f;
  }
  __syncthreads();
  float* dst = xT + ((long)bc * T) * HW + h * 64;
#pragma unroll
  for (int i = 0; i < 16; ++i) {
    int tl = tz * 16 + i;
    int t  = t0 + tl;
    if (t < T) dst[(long)t * HW + tx] = tile[tx][tl];
  }
}

// ---------------------------------------------------------------------------
// async global->LDS, 16 bytes per lane (wave-uniform LDS base + lane*16)
// ---------------------------------------------------------------------------
__device__ __forceinline__ void gload_lds16(const float* g, float* l) {
  __builtin_amdgcn_global_load_lds(
      (const __attribute__((address_space(1))) unsigned int*)g,
      (__attribute__((address_space(3))) unsigned int*)l, 16, 0, 0);
}

// ---------------------------------------------------------------------------
// Kernel A: conv1(5x5 over T,H) + bias + relu + LIF1 + delta -> d8 int8
// d8 layout: [b][t][hw][ci]  (ci contiguous -> stage2 loads 8B per thread)
// block = 512 = (co 0..7) x (w 0..63); grid (b,h,chunk of 4).
// Double-buffered LDS pipeline, superstep S=10: buffer k holds taus
// [ts+3+10k, ts+13+10k) as 100 rows (tau-major, (ci,dh)-minor) of 64 floats
// (128-row buffers incl pad; 64 KiB total -> 2 blocks/CU). 4 staging issues
// of global_load_lds(16B) per thread; counted vmcnt(4) + s_barrier.
// ---------------------------------------------------------------------------
__global__ void __launch_bounds__(512) convlif_kernel(
    const float* __restrict__ xT, const float* __restrict__ w1,
    const float* __restrict__ b1, signed char* __restrict__ d8) {
  __shared__ float buf[2][128 * 64];        // 64 KiB
  const int tid = threadIdx.x;
  const int bid = blockIdx.x;
  const int chunk = bid & 3;
  const int rest  = bid >> 2;
  const int h = rest & 63;
  const int b = rest >> 6;
  const int w  = tid & 63;
  const int co = tid >> 6;                  // == wave id

  // Weights for this co; zero rows whose h+dh-2 is out of range.
  float wt[2][5][5];
#pragma unroll
  for (int ci = 0; ci < 2; ++ci)
#pragma unroll
    for (int dt = 0; dt < 5; ++dt)
#pragma unroll
      for (int dh = 0; dh < 5; ++dh)
        wt[ci][dt][dh] = w1[((co * 2 + ci) * 5 + dt) * 5 + dh];
  float bias = b1[co];

  // Clamped row bases for the one-time window init (global reads).
  const float* basep[2][5];
#pragma unroll
  for (int ci = 0; ci < 2; ++ci)
#pragma unroll
    for (int dh = 0; dh < 5; ++dh) {
      int hh = h + dh - 2;
      bool hv = (hh >= 0) && (hh < H);
      int hc = hh < 0 ? 0 : (hh > H - 1 ? H - 1 : hh);
      basep[ci][dh] = xT + ((long)((b * 2 + ci) * T)) * HW + hc * 64 + w;
      if (!hv) {
#pragma unroll
        for (int dt = 0; dt < 5; ++dt) wt[ci][dt][dh] = 0.0f;
      }
    }

  // Per-thread staging descriptors: 4 issues x 32 rows; row r -> (tau_loc,ci,dh).
  int tloc[4];
  int cpart[4];
#pragma unroll
  for (int i = 0; i < 4; ++i) {
    int r = (tid >> 4) + 32 * i;
    if (r > 99) r = 99;                     // pad rows duplicate row 99
    int tl  = r / 10;
    int rem = r - tl * 10;
    int ci  = rem / 5;
    int dh  = rem - ci * 5;
    int hh = h + dh - 2;
    int hc = hh < 0 ? 0 : (hh > H - 1 ? H - 1 : hh);
    tloc[i]  = tl;
    cpart[i] = ((b * 2 + ci) * T) * HW + hc * 64 + (tid & 15) * 4;
  }

  // chunk c of 4: stored [88c, min(88c+88,350)); 15-step warm-up before.
  const int tstore = chunk * 88;
  const int ts     = chunk ? tstore - 15 : 0;
  const int te     = tstore + 88 < T ? tstore + 88 : T;
  const int nsup   = (te - ts + 9) / 10;

  // Prologue: stage buffer 0 (taus ts+3 .. ts+12).
  {
    int bs = ts + 3;
#pragma unroll
    for (int i = 0; i < 4; ++i) {
      int tau = bs + tloc[i];
      if (tau > T - 1) tau = T - 1;
      gload_lds16(xT + (long)cpart[i] + (long)tau * HW,
                  &buf[0][(i * 32 + co * 4) * 64]);
    }
  }

  // Init sliding window (taus ts-2..ts+2); slot = (tau - ts) mod 5.
  float win[2][5][5];
#pragma unroll
  for (int ci = 0; ci < 2; ++ci)
#pragma unroll
    for (int dh = 0; dh < 5; ++dh) {
      const float* bp = basep[ci][dh];
      win[ci][dh][3] = (ts >= 2) ? bp[(long)(ts - 2) * HW] : 0.0f;
      win[ci][dh][4] = (ts >= 1) ? bp[(long)(ts - 1) * HW] : 0.0f;
      win[ci][dh][0] = bp[(long)(ts + 0) * HW];
      win[ci][dh][1] = bp[(long)(ts + 1) * HW];
      win[ci][dh][2] = bp[(long)(ts + 2) * HW];
    }

  asm volatile("s_waitcnt vmcnt(0)" ::: "memory");
  __builtin_amdgcn_s_barrier();
  asm volatile("" ::: "memory");

  signed char* dsto = d8 + ((long)(b * T) * HW + h * 64 + w) * C1 + co;

  float y = 0.0f, sprev = 0.0f;
  for (int k = 0; k < nsup; ++k) {
    asm volatile("" ::: "memory");
    __builtin_amdgcn_s_barrier();           // prior readers of buf[(k+1)&1] done
    asm volatile("" ::: "memory");
    if (k + 1 < nsup) {
      int bs = ts + 3 + 10 * (k + 1);
      float* nb = &buf[(k + 1) & 1][0];
#pragma unroll
      for (int i = 0; i < 4; ++i) {
        int tau = bs + tloc[i];
        if (tau > T - 1) tau = T - 1;
        gload_lds16(xT + (long)cpart[i] + (long)tau * HW,
                    nb + (i * 32 + co * 4) * 64);
      }
      asm volatile("s_waitcnt vmcnt(4)" ::: "memory");
    } else {
      asm volatile("s_waitcnt vmcnt(0)" ::: "memory");
    }
    __builtin_amdgcn_s_barrier();           // everyone's buf[k&1] rows arrived
    asm volatile("" ::: "memory");

    float* lb = &buf[k & 1][0];
    {
      // zero rows whose tau >= T (only near the end of the last chunk)
      int bufstart = ts + 3 + 10 * k;
      int rz0 = (T - bufstart) * 10;
      if (rz0 < 100) {
        if (rz0 < 0) rz0 = 0;
        for (int r = rz0 + co; r < 100; r += 8) lb[r * 64 + w] = 0.0f;
        asm volatile("" ::: "memory");
        __builtin_amdgcn_s_barrier();
        asm volatile("" ::: "memory");
      }
    }

    const int t0s = ts + 10 * k;
    for (int jj = 0; jj < 2; ++jj) {
#pragma unroll
      for (int u = 0; u < 5; ++u) {
        const int j5 = jj * 5;
        int t = t0s + j5 + u;
        float ac0 = 0.f, ac1 = 0.f, ac2 = 0.f, ac3 = 0.f;
#pragma unroll
        for (int ci = 0; ci < 2; ++ci)
#pragma unroll
          for (int dt = 0; dt < 5; ++dt) {
            const int slot = (u + dt + 3) % 5;
#pragma unroll
            for (int dh = 0; dh < 5; ++dh) {
              const int q = (ci * 25 + dt * 5 + dh) & 3;
              float p = win[ci][dh][slot] * wt[ci][dt][dh];
              if (q == 0) ac0 += p;
              else if (q == 1) ac1 += p;
              else if (q == 2) ac2 += p;
              else ac3 += p;
            }
          }
        float a = ((ac0 + ac1) + (ac2 + ac3)) + bias;
        a = fmaxf(a, 0.0f);
        y = fmaf(DEC, y, a);
        float s = (y >= 1.0f) ? 1.0f : 0.0f;
        if (t >= tstore && t < te) {
          float dlt = (t == 0) ? 0.0f : (s - sprev);
          dsto[(long)t * (HW * C1)] = (signed char)dlt;
        }
        sprev = s;
        y = (s != 0.0f) ? 0.0f : y;
        // slide: tau = t+3 lives at LDS row ((j5+u)*10 + ci*5 + dh)
        const int slot2 = (u + 3) % 5;
#pragma unroll
        for (int ci = 0; ci < 2; ++ci)
#pragma unroll
          for (int dh = 0; dh < 5; ++dh)
            win[ci][dh][slot2] = lb[((j5 + u) * 10 + ci * 5 + dh) * 64 + w];
      }
    }
  }
}

// ---------------------------------------------------------------------------
// Kernel B: deconv(2x2,s2) + bias + relu + conv2(1x1) + LIF2 -> out
// d8 now [b][t][hw][ci]: one 8B uint2 load per pair-step (512B/wave),
// register-prefetched one iteration ahead; unpack via bfe+cvt.
// out layout [B,2,H',W',T']; LDS-staged transposed flush. 16 chunks
// (chunk in low bits -> accidental chunk->XCD L2 affinity, keep it).
// ---------------------------------------------------------------------------
__global__ void __launch_bounds__(64) stage2_kernel(
    const signed char* __restrict__ d8, const float* __restrict__ dw,
    const float* __restrict__ db, const float* __restrict__ cw,
    const float* __restrict__ cb, float* __restrict__ out) {
  __shared__ float SB[2][64][17];
  int bid   = blockIdx.x;
  int chunk = bid & 15;           // 16 chunks over T'=700
  int rest  = bid >> 4;
  int hp = rest & 127;            // h'
  int b  = rest >> 7;
  int wp = threadIdx.x;           // w'

  int h  = hp >> 1;
  int kh = 1 - (hp & 1);

  // deconv weights for this kh, both kt parities: dwk{kt}[c][ci]
  float dwk0[2][8], dwk1[2][8];
#pragma unroll
  for (int c = 0; c < 2; ++c)
#pragma unroll
    for (int ci = 0; ci < 8; ++ci) {
      dwk0[c][ci] = dw[((c * 8 + ci) * 2 + 0) * 2 + kh];
      dwk1[c][ci] = dw[((c * 8 + ci) * 2 + 1) * 2 + kh];
    }
  float db0 = db[0], db1 = db[1];
  float cw00 = cw[0], cw01 = cw[1], cw10 = cw[2], cw11 = cw[3];
  float cb0 = cb[0], cb1 = cb[1];

  int t0 = chunk * 44;
  int t1 = (t0 + 44 < TO) ? t0 + 44 : TO;   // last chunk: 40
  int tw = (t0 - 16 > 0) ? t0 - 16 : 0;     // 16-step LIF2 warm-up (even)

  const signed char* dbase = d8 + (((long)b * T) * HW + h * 64 + wp) * C1;
  const long tstride = (long)HW * C1;       // bytes per t
  float* outb = out + ((long)b * 2 * HO) * (long)(WO * TO);

  float y0 = 0.0f, y1 = 0.0f;
  uint2 dc = *reinterpret_cast<const uint2*>(dbase + (long)(tw >> 1) * tstride);
  for (int tp = tw; tp < t1; tp += 2) {
    int tn = (tp + 2 < t1) ? ((tp + 2) >> 1) : ((t1 - 1) >> 1);
    uint2 dn = *reinterpret_cast<const uint2*>(dbase + (long)tn * tstride);

    float dv[8];
#pragma unroll
    for (int ci = 0; ci < 4; ++ci) {
      dv[ci]     = (float)(signed char)((dc.x >> (8 * ci)) & 0xff);
      dv[ci + 4] = (float)(signed char)((dc.y >> (8 * ci)) & 0xff);
    }

#pragma unroll
    for (int par = 0; par < 2; ++par) {     // par=0: tp (kt=1), par=1: tp+1 (kt=0)
      int tpp = tp + par;
      float v0 = db0, v1 = db1;
      if (par == 0) {
#pragma unroll
        for (int ci = 0; ci < 8; ++ci) {
          v0 = fmaf(dv[ci], dwk1[0][ci], v0);
          v1 = fmaf(dv[ci], dwk1[1][ci], v1);
        }
      } else {
#pragma unroll
        for (int ci = 0; ci < 8; ++ci) {
          v0 = fmaf(dv[ci], dwk0[0][ci], v0);
          v1 = fmaf(dv[ci], dwk0[1][ci], v1);
        }
      }
      v0 = fmaxf(v0, 0.0f);
      v1 = fmaxf(v1, 0.0f);
      float u0 = fmaf(cw00, v0, fmaf(cw01, v1, cb0));
      float u1 = fmaf(cw10, v0, fmaf(cw11, v1, cb1));
      y0 = fmaf(DEC, y0, u0);
      y1 = fmaf(DEC, y1, u1);
      float s0 = (y0 >= 1.0f) ? 1.0f : 0.0f;
      float s1 = (y1 >= 1.0f) ? 1.0f : 0.0f;
      y0 = (s0 != 0.0f) ? 0.0f : y0;
      y1 = (s1 != 0.0f) ? 0.0f : y1;

      if (tpp >= t0) {
        int k = (tpp - t0) & 15;
        SB[0][wp][k] = s0;
        SB[1][wp][k] = s1;
        if (par == 1 && (k == 15 || tpp == t1 - 1)) {
          __syncthreads();
          int Kc  = k + 1;                  // 16 or a multiple of 4
          int t0f = tpp - k;
#pragma unroll
          for (int o = 0; o < 2; ++o) {
            float* ob = outb + ((long)(o * HO + hp)) * (long)(WO * TO);
#pragma unroll
            for (int i = 0; i < 4; ++i) {
              int idx = (i << 6) + wp;
              int r   = idx >> 2;
              int c   = (idx & 3) << 2;
              if (c < Kc) {
                float4 vv;
                vv.x = SB[o][r][c + 0];
                vv.y = SB[o][r][c + 1];
                vv.z = SB[o][r][c + 2];
                vv.w = SB[o][r][c + 3];
                *reinterpret_cast<float4*>(ob + (long)r * TO + (t0f + c)) = vv;
              }
            }
          }
          __syncthreads();
        }
      }
    }
    dc = dn;
  }
}

// ---------------------------------------------------------------------------
extern "C" void kernel_launch(void* const* d_in, const int* in_sizes, int n_in,
                              void* d_out, int out_size, void* d_ws, size_t ws_size,
                              hipStream_t stream) {
  const float* x  = (const float*)d_in[0];
  const float* w1 = (const float*)d_in[1];
  const float* b1 = (const float*)d_in[2];
  const float* dw = (const float*)d_in[3];
  const float* db = (const float*)d_in[4];
  const float* cw = (const float*)d_in[5];
  const float* cb = (const float*)d_in[6];
  float* out = (float*)d_out;

  float* xT = (float*)d_ws;                                   // 22.94 MB
  signed char* d8 = (signed char*)d_ws + (size_t)B * CIN * T * HW * 4;  // +22.94 MB

  // 1) transpose x -> xT
  transpose_kernel<<<dim3(B * CIN * H * 6), dim3(256), 0, stream>>>(x, xT);
  // 2) conv1+relu+LIF1+delta -> d8 (4 T-chunks, LDS-pipelined, S=10)
  convlif_kernel<<<dim3(B * H * 4), dim3(512), 0, stream>>>(xT, w1, b1, d8);
  // 3) deconv+relu+conv2+LIF2 -> out (16 T'-chunks, uint2 prefetch)
  stage2_kernel<<<dim3(B * HO * 16), dim3(64), 0, stream>>>(d8, dw, db, cw, cb, out);
}